// Round 1
// 362.815 us; speedup vs baseline: 1.0067x; 1.0067x over previous
//
#include <hip/hip_runtime.h>

#define T 32
#define C_IN 64
#define H 128
#define W 128
#define C_OUT 128
#define KH 5
#define KW 5
#define H_OUT 124
#define W_OUT 124
#define K_WINNERS 256
#define LR_PLUS 0.004f
#define LR_MINUS -0.003f

// ---- Kernel 1: in_lat[ci][h][w] = sum_t in_spikes[t][ci][h][w] -------------
// Pure streaming reduction over the t axis. Per t-slice the whole grid reads
// contiguously (float4, 1 KB per wave-instruction), 32 independent loads per
// thread pipelined under vmcnt. 134 MB read + 4 MB write => ~22 us at ~6 TB/s.
// Sums of 0/1 floats (<=32) are exact in fp32 regardless of order => bit-exact
// vs the reference's in_lat.
#define LAT_ELEMS (C_IN * H * W)        // 1048576 floats = 4 MB
#define LAT_VEC4  (LAT_ELEMS / 4)       // 262144 float4
#define SUM_BLOCK 256
#define SUM_GRID  (LAT_VEC4 / SUM_BLOCK) // 1024 blocks -> 4096 waves, 16/CU

__global__ __launch_bounds__(SUM_BLOCK) void sum_over_t(
        const float4* __restrict__ in4, float4* __restrict__ lat4) {
    const int i = blockIdx.x * SUM_BLOCK + threadIdx.x;   // < LAT_VEC4
    float4 s = make_float4(0.f, 0.f, 0.f, 0.f);
    #pragma unroll
    for (int t = 0; t < T; ++t) {
        float4 v = in4[(size_t)t * LAT_VEC4 + i];
        s.x += v.x; s.y += v.y; s.z += v.z; s.w += v.w;
    }
    lat4[i] = s;
}

// ---- Kernel 2: winner scan + STDP apply ------------------------------------
// 5 blocks per filter (block-uniform f => no divergence on the winner branch).
// Patch values now come from the 4 MB in_lat (L2/L3 resident): one cached load
// per weight element instead of 32 scattered HBM gathers.
#define BLOCKS_PER_F 5
#define BLOCK 320  // BLOCKS_PER_F*BLOCK = 1600 = C_IN*KH*KW exactly

__global__ __launch_bounds__(BLOCK) void stdp_apply(
        const float* __restrict__ lat,
        const float* __restrict__ out_spikes,
        const float* __restrict__ weight,
        const int* __restrict__ winners,
        float* __restrict__ out) {
    __shared__ int s_k;
    __shared__ float s_part[T];
    __shared__ float s_outval;

    const int f = blockIdx.x / BLOCKS_PER_F;
    const int tid = threadIdx.x;

    if (tid == 0) s_k = -1;
    __syncthreads();
    // Reference scan-overwrite semantics: LAST winner with winners[k][0]==f.
    if (tid < K_WINNERS && winners[tid * 3] == f)
        atomicMax(&s_k, tid);
    __syncthreads();
    const int k = s_k;

    int r0 = 0, c0 = 0;
    if (k >= 0) {
        r0 = winners[k * 3 + 1];  // block-uniform address -> broadcast load
        c0 = winners[k * 3 + 2];
        if (tid < T) {
            s_part[tid] = out_spikes[(size_t)tid * (C_OUT * H_OUT * W_OUT)
                                     + (size_t)f * (H_OUT * W_OUT)
                                     + (size_t)r0 * W_OUT + c0];
        }
    }
    __syncthreads();
    if (k >= 0 && tid == 0) {
        float v = 0.0f;
        #pragma unroll
        for (int t = 0; t < T; ++t) v += s_part[t];  // exact integer sum
        s_outval = v;
    }
    __syncthreads();

    const int rem = (blockIdx.x % BLOCKS_PER_F) * BLOCK + tid;  // 0..1599
    const int idx = f * (C_IN * KH * KW) + rem;
    float w = weight[idx];
    float res;
    if (k < 0) {
        res = w;  // lr == 0: weight unchanged (clip is no-op for w in [0,1])
    } else {
        const int ci = rem / (KH * KW);
        const int p  = rem % (KH * KW);
        const int r  = r0 + p / KW;   // < 124 + 4 < 128: in bounds
        const int c  = c0 + p % KW;
        const float sum = lat[(size_t)ci * (H * W) + (size_t)r * W + c];
        float lr = (sum >= s_outval) ? LR_PLUS : LR_MINUS;
        res = w + lr * w * (1.0f - w);
    }
    out[idx] = fminf(fmaxf(res, 0.0f), 1.0f);
}

extern "C" void kernel_launch(void* const* d_in, const int* in_sizes, int n_in,
                              void* d_out, int out_size, void* d_ws, size_t ws_size,
                              hipStream_t stream) {
    const float* in_spikes  = (const float*)d_in[0];  // (T, C_IN, H, W)
    const float* out_spikes = (const float*)d_in[1];  // (T, C_OUT, H_OUT, W_OUT)
    const float* weight     = (const float*)d_in[2];  // (C_OUT, C_IN, KH, KW)
    const int*   winners    = (const int*)d_in[3];    // (K_WINNERS, 3)
    float* lat = (float*)d_ws;                        // 4 MB of workspace

    sum_over_t<<<SUM_GRID, SUM_BLOCK, 0, stream>>>(
        (const float4*)in_spikes, (float4*)lat);
    stdp_apply<<<C_OUT * BLOCKS_PER_F, BLOCK, 0, stream>>>(
        lat, out_spikes, weight, winners, (float*)d_out);
}